// Round 9
// baseline (146.925 us; speedup 1.0000x reference)
//
#include <hip/hip_runtime.h>
#include <math.h>

#define WIN 11
#define IMG_H 384
#define IMG_W 512
#define OUT_H (IMG_H - WIN + 1)   // 374
#define OUT_W (IMG_W - WIN + 1)   // 502
#define RPW 2                     // output rows per pair-unit
#define NPAIRS 187                // per image (exact: 374 = 2*187)
#define NIMG 48
#define TOTAL_PAIRS (NPAIRS * NIMG)   // 8976
#define PPW 3                     // pairs per wave, sequential (r21)
#define WPB 4                     // independent waves per block (no barriers)
#define NBLOCKS 752               // 8*94; 752*4*3 = 9024 >= 8976 (48 pad units)
#define BPX 94                    // blocks per XCD
#define NBUCKETS 256

typedef float v2 __attribute__((ext_vector_type(2)));

struct GaussW { float g[WIN]; };
struct Row { float4 xa, xb, ya, yb; };

__device__ __forceinline__ v2 shfl_v2(v2 v, int src) {
    v2 r; r.x = __shfl(v.x, src, 64); r.y = __shfl(v.y, src, 64); return r;
}

__device__ __forceinline__ void horiz11_v2(const v2 (&A)[8], v2 (&out)[8],
                                           int lane, const GaussW& gw)
{
    v2 V[18];
    #pragma unroll
    for (int j = 0; j < 8; ++j) V[j] = A[j];
    #pragma unroll
    for (int j = 0; j < 8; ++j) V[8 + j] = shfl_v2(A[j], lane + 1);
    V[16] = shfl_v2(A[0], lane + 2);
    V[17] = shfl_v2(A[1], lane + 2);
    #pragma unroll
    for (int j = 0; j < 8; ++j) {
        v2 o = 0.f;
        #pragma unroll
        for (int k = 0; k < WIN; ++k) {
            v2 g = gw.g[k];
            o = __builtin_elementwise_fma(g, V[j + k], o);  // v_pk_fma_f32
        }
        out[j] = o;
    }
}

__device__ __forceinline__ void horiz11_f(const float (&A)[8], float (&out)[8],
                                          int lane, const GaussW& gw)
{
    float V[18];
    #pragma unroll
    for (int j = 0; j < 8; ++j) V[j] = A[j];
    #pragma unroll
    for (int j = 0; j < 8; ++j) V[8 + j] = __shfl(A[j], lane + 1, 64);
    V[16] = __shfl(A[0], lane + 2, 64);
    V[17] = __shfl(A[1], lane + 2, 64);
    #pragma unroll
    for (int j = 0; j < 8; ++j) {
        float o = 0.f;
        #pragma unroll
        for (int k = 0; k < WIN; ++k) o = fmaf(gw.g[k], V[j + k], o);
        out[j] = o;
    }
}

// r21 vs r20 (44.8us, VALU 55%, Occ 17%): persistent waves + cross-pair
// pipelining. 752 blocks x 4 waves, each wave owns 3 CONSECUTIVE pairs.
// (1) Single dispatch generation: all 752 blocks co-resident (cap 1024 at
//     this VGPR) -> occupancy flat ~37% instead of a 2.2x ramp of 5us blocks.
// (2) Pair p+1's 3-row warm-up loads issue BEFORE pair p's horizontal pass
//     (~1200 cy of register/bpermute work) -> warm-up latency hidden for
//     pairs 2,3; within-pair loads keep r20's 3-phase fenced lookahead.
// (3) Consecutive pairs re-read 10 of 12 rows -> L1-hot vertical loads.
// (4) k==r first-touch write elides all 80 accumulator zero-init movs/pair.
// Still: no LDS, no barriers, waves fully independent (r13/r14/r19 lesson).
__global__ __launch_bounds__(256) void ssim_fused_kernel(
    const float* __restrict__ X, const float* __restrict__ Y,
    double* __restrict__ accum, GaussW gw)
{
    const int wave = threadIdx.x >> 6;
    const int lane = threadIdx.x & 63;

    // Block-level XCD swizzle (bijective: 752 = 8*94); a block's 4 waves
    // cover 12 consecutive pairs = 24 contiguous output rows.
    const int id = blockIdx.x;
    const int wb = (id & 7) * BPX + (id >> 3);
    const int P0 = (wb * WPB + wave) * PPW;    // first pair of this wave
    const int c0 = lane << 3;                  // this lane's 8 columns

    #define LOADROW(B, K) {                                                  \
        const float* _rx = Xb + (size_t)(K) * IMG_W;                         \
        const float* _ry = Yb + (size_t)(K) * IMG_W;                         \
        (B).xa = *(const float4*)(_rx);                                      \
        (B).xb = *(const float4*)(_rx + 4);                                  \
        (B).ya = *(const float4*)(_ry);                                      \
        (B).yb = *(const float4*)(_ry + 4);                                  \
    }
    #define PAIR_BASES(PC) {                                                 \
        const int _img  = (PC) / NPAIRS;                                     \
        const int _pair = (PC) - _img * NPAIRS;                              \
        const int _r0   = _pair * RPW;        /* max input row 383 */        \
        Xb = X + ((size_t)_img * IMG_H + _r0) * IMG_W + c0;                  \
        Yb = Y + ((size_t)_img * IMG_H + _r0) * IMG_W + c0;                  \
    }

    const float* Xb; const float* Yb;
    {   // prologue: pair 0 bases + 3-row warm-up
        const int Pc = (P0 < TOTAL_PAIRS) ? P0 : (TOTAL_PAIRS - 1);
        PAIR_BASES(Pc);
    }
    Row buf[3];
    LOADROW(buf[0], 0); LOADROW(buf[1], 1); LOADROW(buf[2], 2);
    __builtin_amdgcn_sched_barrier(0);

    for (int p = 0; p < PPW; ++p) {
        // Accumulators: a01 = {m1,m2}, a23 = {xx,yy}, a4 = xy (tensor-packed).
        // No zero-init: first touch at phase k==r writes instead of fma.
        v2 a01[RPW][8], a23[RPW][8];
        float a4[RPW][8];

        #pragma unroll
        for (int k = 0; k < RPW + WIN - 1; ++k) {   // 12 input rows
            Row cur = buf[k % 3];                   // SSA: no real copy
            // Refill slot with row k+3 (3 fenced phases of latency lead).
            if (k + 3 < RPW + WIN - 1) LOADROW(buf[k % 3], k + 3);

            v2 pk[8] = {{cur.xa.x, cur.ya.x}, {cur.xa.y, cur.ya.y},
                        {cur.xa.z, cur.ya.z}, {cur.xa.w, cur.ya.w},
                        {cur.xb.x, cur.yb.x}, {cur.xb.y, cur.yb.y},
                        {cur.xb.z, cur.yb.z}, {cur.xb.w, cur.yb.w}};
            #pragma unroll
            for (int r = 0; r < RPW; ++r) {
                if (k - r >= 0 && k - r < WIN) {     // compile-time
                    v2 g = gw.g[k - r];
                    #pragma unroll
                    for (int j = 0; j < 8; ++j) {
                        v2 q = pk[j];
                        v2 t = g * q;                              // {gx, gy}
                        if (k == r) {                // first touch: no init
                            a01[r][j] = t;
                            a23[r][j] = t * q;
                            a4[r][j]  = t.x * q.y;
                        } else {
                            a01[r][j] = __builtin_elementwise_fma(g, q, a01[r][j]);
                            a23[r][j] = __builtin_elementwise_fma(t, q, a23[r][j]);
                            a4[r][j]  = fmaf(t.x, q.y, a4[r][j]);  // g*x*y
                        }
                    }
                }
            }
            __builtin_amdgcn_sched_barrier(0);      // phase fence
        }

        // Cross-pair pipeline: issue next pair's 3-row warm-up NOW, then do
        // this pair's horizontal (loads drain under ~1200cy of VALU/bperm).
        if (p + 1 < PPW) {
            const int Pn = (P0 + p + 1 < TOTAL_PAIRS) ? (P0 + p + 1)
                                                      : (TOTAL_PAIRS - 1);
            PAIR_BASES(Pn);
            LOADROW(buf[0], 0); LOADROW(buf[1], 1); LOADROW(buf[2], 2);
        }
        __builtin_amdgcn_sched_barrier(0);

        // ---- horizontal + epilogue (registers/bpermute only) ----
        const float C1 = 1e-4f, C2 = 9e-4f;
        float sum = 0.f;
        #pragma unroll
        for (int r = 0; r < RPW; ++r) {
            v2 h01[8], h23[8];
            float h4[8];
            horiz11_v2(a01[r], h01, lane, gw);
            horiz11_v2(a23[r], h23, lane, gw);
            horiz11_f (a4[r],  h4,  lane, gw);
            #pragma unroll
            for (int j = 0; j < 8; ++j) {
                v2 mu = h01[j];
                v2 sq = mu * mu;                    // {mu1², mu2²}
                float m12 = mu.x * mu.y;
                v2 sig = h23[j] - sq;               // {s1, s2}
                float s12 = h4[j] - m12;
                float num = fmaf(2.f, m12, C1) * fmaf(2.f, s12, C2);
                float den = (sq.x + sq.y + C1) * (sig.x + sig.y + C2);
                float ssim = num * __builtin_amdgcn_rcpf(den);
                sum += (c0 + j < OUT_W) ? ssim : 0.f;
            }
        }

        // ---- wave reduction -> one f64 atomic per valid pair, bucketed ----
        #pragma unroll
        for (int off = 32; off; off >>= 1)
            sum += __shfl_down(sum, off, 64);
        if (lane == 0 && P0 + p < TOTAL_PAIRS)
            atomicAdd(&accum[(P0 + p) & (NBUCKETS - 1)], (double)sum);
    }
    #undef LOADROW
    #undef PAIR_BASES
}

__global__ void ssim_finalize_kernel(const double* __restrict__ accum,
                                     float* __restrict__ out, double inv_count)
{
    const int lane = threadIdx.x;
    double s = 0.0;
    for (int i = lane; i < NBUCKETS; i += 64) s += accum[i];
    #pragma unroll
    for (int off = 32; off; off >>= 1)
        s += __shfl_down(s, off, 64);
    if (lane == 0) out[0] = (float)(1.0 - s * inv_count);
}

extern "C" void kernel_launch(void* const* d_in, const int* in_sizes, int n_in,
                              void* d_out, int out_size, void* d_ws, size_t ws_size,
                              hipStream_t stream) {
    const float* X = (const float*)d_in[0];
    const float* Y = (const float*)d_in[1];
    float* out = (float*)d_out;
    double* accum = (double*)d_ws;

    GaussW gw;
    {
        double g[WIN], ssum = 0.0;
        for (int i = 0; i < WIN; ++i) {
            double d = (double)i - WIN / 2;
            g[i] = exp(-(d * d) / (2.0 * 1.5 * 1.5));
            ssum += g[i];
        }
        for (int i = 0; i < WIN; ++i) gw.g[i] = (float)(g[i] / ssum);
    }

    // d_ws is re-poisoned 0xAA before every call — zero the buckets.
    hipMemsetAsync(accum, 0, NBUCKETS * sizeof(double), stream);

    ssim_fused_kernel<<<NBLOCKS, 64 * WPB, 0, stream>>>(X, Y, accum, gw);

    const double inv_count = 1.0 / ((double)NIMG * OUT_H * OUT_W);
    ssim_finalize_kernel<<<1, 64, 0, stream>>>(accum, out, inv_count);
}

// Round 10
// 130.296 us; speedup vs baseline: 1.1276x; 1.1276x over previous
//
#include <hip/hip_runtime.h>
#include <math.h>

#define WIN 11
#define IMG_H 384
#define IMG_W 512
#define OUT_H (IMG_H - WIN + 1)   // 374
#define OUT_W (IMG_W - WIN + 1)   // 502
#define RPW 2                     // output rows per wave (RPW=4 refuted r18)
#define NPAIRS 187                // per image (exact: 374 = 2*187)
#define NIMG 48
#define TOTAL_PAIRS (NPAIRS * NIMG)   // 8976
#define WPB 4                     // 4 waves/block proven best (8 refuted r19)
#define NBLOCKS 2248              // ceil(8976/4) padded to 8*281 for swizzle
#define BPX 281                   // blocks per XCD
#define NBUF 5                    // r22: rolling pipeline depth (r20 had 3)
#define NBUCKETS 256              // fallback mode only

typedef float v2 __attribute__((ext_vector_type(2)));

struct GaussW { float g[WIN]; };
struct Row { float4 xa, xb, ya, yb; };

__device__ __forceinline__ v2 shfl_v2(v2 v, int src) {
    v2 r; r.x = __shfl(v.x, src, 64); r.y = __shfl(v.y, src, 64); return r;
}

__device__ __forceinline__ void horiz11_v2(const v2 (&A)[8], v2 (&out)[8],
                                           int lane, const GaussW& gw)
{
    v2 V[18];
    #pragma unroll
    for (int j = 0; j < 8; ++j) V[j] = A[j];
    #pragma unroll
    for (int j = 0; j < 8; ++j) V[8 + j] = shfl_v2(A[j], lane + 1);
    V[16] = shfl_v2(A[0], lane + 2);
    V[17] = shfl_v2(A[1], lane + 2);
    #pragma unroll
    for (int j = 0; j < 8; ++j) {
        v2 o = 0.f;
        #pragma unroll
        for (int k = 0; k < WIN; ++k) {
            v2 g = gw.g[k];
            o = __builtin_elementwise_fma(g, V[j + k], o);  // v_pk_fma_f32
        }
        out[j] = o;
    }
}

__device__ __forceinline__ void horiz11_f(const float (&A)[8], float (&out)[8],
                                          int lane, const GaussW& gw)
{
    float V[18];
    #pragma unroll
    for (int j = 0; j < 8; ++j) V[j] = A[j];
    #pragma unroll
    for (int j = 0; j < 8; ++j) V[8 + j] = __shfl(A[j], lane + 1, 64);
    V[16] = __shfl(A[0], lane + 2, 64);
    V[17] = __shfl(A[1], lane + 2, 64);
    #pragma unroll
    for (int j = 0; j < 8; ++j) {
        float o = 0.f;
        #pragma unroll
        for (int k = 0; k < WIN; ++k) o = fmaf(gw.g[k], V[j + k], o);
        out[j] = o;
    }
}

// r22 vs r20 (44.8us best, VGPR 88, VALU 55%): three low-risk levers on the
// SAME skeleton (r18/r19/r21 all showed structural changes lose via VGPR/
// residency):
// (1) pipeline depth 3 -> 5 (lead ~750cy): r20's lead-3 (~450cy) covers L2
//     (~200cy) but not HBM (~900cy); FETCH=37MB says ~half the rows miss to
//     HBM and stall ~450cy each at lead-3. Cost +32 VGPR, est ~120 <= 128
//     tier boundary (the hard law from r18/r21: never cross 128).
// (2) first-touch accumulator init (k==r writes product, bit-identical to
//     fma-into-zero): deletes the 80 zero-init movs per pair.
// (3) no memset + no f64 atomics: each pair's sum goes to a UNIQUE d_ws
//     slot (poison fully overwritten), finalize reduces 8976 doubles in
//     deterministic order; one fewer stream op. Bucket+memset fallback if
//     ws_size is too small.
__global__ __launch_bounds__(256) void ssim_fused_kernel(
    const float* __restrict__ X, const float* __restrict__ Y,
    double* __restrict__ slots, GaussW gw, int flat)
{
    const int wave = threadIdx.x >> 6;
    const int lane = threadIdx.x & 63;

    // Block-level XCD swizzle; waves in a block take adjacent row-pairs
    // (shared halo rows hit L1/L2).
    const int id = blockIdx.x;
    const int wb = (id & 7) * BPX + (id >> 3);
    const int P  = wb * WPB + wave;        // global row-pair index
    if (P >= TOTAL_PAIRS) return;          // 16 pad waves; no barriers -> safe

    const int img  = P / NPAIRS;
    const int pair = P % NPAIRS;
    const int r0   = pair * RPW;          // max input row = 372+11 = 383
    const int c0   = lane << 3;           // this lane's 8 columns
    const float* __restrict__ Xb = X + ((size_t)img * IMG_H + r0) * IMG_W + c0;
    const float* __restrict__ Yb = Y + ((size_t)img * IMG_H + r0) * IMG_W + c0;

    // Accumulators: a01 = {m1,m2}, a23 = {xx,yy}, a4 = xy (tensor-packed).
    // No zero-init: first touch at phase k==r writes the product directly.
    v2 a01[RPW][8], a23[RPW][8];
    float a4[RPW][8];

    #define LOADROW(B, K) {                                                  \
        const float* _rx = Xb + (size_t)(K) * IMG_W;                         \
        const float* _ry = Yb + (size_t)(K) * IMG_W;                         \
        (B).xa = *(const float4*)(_rx);                                      \
        (B).xb = *(const float4*)(_rx + 4);                                  \
        (B).ya = *(const float4*)(_ry);                                      \
        (B).yb = *(const float4*)(_ry + 4);                                  \
    }

    Row buf[NBUF];
    #pragma unroll
    for (int w = 0; w < NBUF; ++w) LOADROW(buf[w], w);   // warm-up: 5 rows
    __builtin_amdgcn_sched_barrier(0);

    #pragma unroll
    for (int k = 0; k < RPW + WIN - 1; ++k) {   // 12 input rows
        Row cur = buf[k % NBUF];                // SSA: no real copy
        // Refill slot with row k+NBUF (5 fenced phases of latency lead).
        if (k + NBUF < RPW + WIN - 1) LOADROW(buf[k % NBUF], k + NBUF);

        v2 pk[8] = {{cur.xa.x, cur.ya.x}, {cur.xa.y, cur.ya.y},
                    {cur.xa.z, cur.ya.z}, {cur.xa.w, cur.ya.w},
                    {cur.xb.x, cur.yb.x}, {cur.xb.y, cur.yb.y},
                    {cur.xb.z, cur.yb.z}, {cur.xb.w, cur.yb.w}};
        #pragma unroll
        for (int r = 0; r < RPW; ++r) {
            if (k - r >= 0 && k - r < WIN) {     // compile-time after unroll
                v2 g = gw.g[k - r];
                #pragma unroll
                for (int j = 0; j < 8; ++j) {
                    v2 q = pk[j];
                    v2 t = g * q;                              // {gx, gy}
                    if (k == r) {                // first touch: no zero-init
                        a01[r][j] = t;
                        a23[r][j] = t * q;
                        a4[r][j]  = t.x * q.y;
                    } else {
                        a01[r][j] = __builtin_elementwise_fma(g, q, a01[r][j]);
                        a23[r][j] = __builtin_elementwise_fma(t, q, a23[r][j]);
                        a4[r][j]  = fmaf(t.x, q.y, a4[r][j]);  // g*x*y
                    }
                }
            }
        }
        __builtin_amdgcn_sched_barrier(0);      // phase fence: no load sinking
    }
    #undef LOADROW

    // ---- horizontal + epilogue per row (registers/bpermute only) ----
    const float C1 = 1e-4f, C2 = 9e-4f;
    float sum = 0.f;
    #pragma unroll
    for (int r = 0; r < RPW; ++r) {
        v2 h01[8], h23[8];
        float h4[8];
        horiz11_v2(a01[r], h01, lane, gw);
        horiz11_v2(a23[r], h23, lane, gw);
        horiz11_f (a4[r],  h4,  lane, gw);
        #pragma unroll
        for (int j = 0; j < 8; ++j) {
            v2 mu = h01[j];
            v2 sq = mu * mu;                    // {mu1², mu2²}
            float m12 = mu.x * mu.y;
            v2 sig = h23[j] - sq;               // {s1, s2}
            float s12 = h4[j] - m12;
            float num = fmaf(2.f, m12, C1) * fmaf(2.f, s12, C2);
            float den = (sq.x + sq.y + C1) * (sig.x + sig.y + C2);
            float ssim = num * __builtin_amdgcn_rcpf(den);
            sum += (c0 + j < OUT_W) ? ssim : 0.f;
        }
    }

    // ---- wave reduction -> one f64 write per pair ----
    #pragma unroll
    for (int off = 32; off; off >>= 1)
        sum += __shfl_down(sum, off, 64);
    if (lane == 0) {
        if (flat) slots[P] = (double)sum;                    // unique slot
        else atomicAdd(&slots[P & (NBUCKETS - 1)], (double)sum);
    }
}

__global__ void ssim_finalize_kernel(const double* __restrict__ slots,
                                     float* __restrict__ out,
                                     double inv_count, int count)
{
    const int tid  = threadIdx.x;          // 256 threads
    const int wave = tid >> 6, lane = tid & 63;
    __shared__ double ws[4];
    double s = 0.0;
    for (int i = tid; i < count; i += 256) s += slots[i];
    #pragma unroll
    for (int off = 32; off; off >>= 1)
        s += __shfl_down(s, off, 64);
    if (lane == 0) ws[wave] = s;
    __syncthreads();
    if (tid == 0)
        out[0] = (float)(1.0 - (ws[0] + ws[1] + ws[2] + ws[3]) * inv_count);
}

extern "C" void kernel_launch(void* const* d_in, const int* in_sizes, int n_in,
                              void* d_out, int out_size, void* d_ws, size_t ws_size,
                              hipStream_t stream) {
    const float* X = (const float*)d_in[0];
    const float* Y = (const float*)d_in[1];
    float* out = (float*)d_out;
    double* slots = (double*)d_ws;

    GaussW gw;
    {
        double g[WIN], ssum = 0.0;
        for (int i = 0; i < WIN; ++i) {
            double d = (double)i - WIN / 2;
            g[i] = exp(-(d * d) / (2.0 * 1.5 * 1.5));
            ssum += g[i];
        }
        for (int i = 0; i < WIN; ++i) gw.g[i] = (float)(g[i] / ssum);
    }

    // Flat mode: one slot per pair, every slot overwritten -> no zeroing
    // needed (d_ws is re-poisoned 0xAA before every call). Fallback to
    // bucket+memset if the workspace is too small.
    const int flat = (ws_size >= (size_t)TOTAL_PAIRS * sizeof(double)) ? 1 : 0;
    if (!flat)
        hipMemsetAsync(slots, 0, NBUCKETS * sizeof(double), stream);

    ssim_fused_kernel<<<NBLOCKS, 64 * WPB, 0, stream>>>(X, Y, slots, gw, flat);

    const double inv_count = 1.0 / ((double)NIMG * OUT_H * OUT_W);
    ssim_finalize_kernel<<<1, 256, 0, stream>>>(
        slots, out, inv_count, flat ? TOTAL_PAIRS : NBUCKETS);
}